// Round 4
// baseline (468.430 us; speedup 1.0000x reference)
//
#include <hip/hip_runtime.h>
#include <math.h>

// ChamferLoss: pred [32,4096,3] f32, gt [32,4096,3] f32 -> scalar f32.
//
// R8 = R7 (MFMA rewrite) with two fixes:
//  1. BUG: chamfer_prep grid was 512 blocks (131072 threads) but Bfrag
//     needs 32 x 256 x 64 = 524288 -> batches 8..31 read garbage
//     (absmax 468). Grid is now 2048 blocks.
//  2. Epilogue was still 3.5 VALU/pair (same as the scalar roofline kernel).
//     Now the FULL distance comes out of the MFMA: K-slots 0-17 carry the
//     dot products of (-2*gt) x pred (3-way bf16 split, products
//     hh,hm,mh,hl,lh,mm), slots 18-20 carry split3(g2) x 1.0, slots 21-23
//     carry 1.0 x split3(p2). acc == d2 directly -> epilogue is
//     1 v_min (gt row-min) + 0.5 v_min3 (pred col fold) per pair.
//     p2arr eliminated.
//
// Cycle model: per s-iter/wave 4 MFMA + ~30 VALU (16 min, 8 min3, 2 shfl,
// guard) vs R6's 204 cy. Predicted main ~30-40us.
//
// Layouts (m89-verified family, 16x16x32 bf16):
//   A: row = lane&15, k = 8*(lane>>4)+i
//   B: col = lane&15, k = 8*(lane>>4)+i
//   C: col = lane&15, row = 4*(lane>>4)+reg

typedef short short8 __attribute__((ext_vector_type(8)));
typedef float f32x4 __attribute__((ext_vector_type(4)));
typedef unsigned int uint;

#define NPTS  4096
#define TPBM  512           // main: 8 waves = rowhalf(2) x colquarter(4)
#define TPBP  256
#define PANELS 32           // gt row-panels of 128 per batch
#define GRID_MAIN (32 * PANELS)
#define GRID_PREP ((32 * 256 * 64) / TPBP)   // 2048: one thread per frag-lane
#define ONEB ((short)0x3F80)                 // bf16 1.0

__device__ unsigned int g_done[32];   // zero-init; self-resetting per replay

// ---- bf16 split helpers (RNE) ----
__device__ __forceinline__ unsigned short bf16h(float f) {
    uint u = __float_as_uint(f);
    uint r = u + 0x7FFFu + ((u >> 16) & 1u);
    return (unsigned short)(r >> 16);
}
__device__ __forceinline__ float bf16f(unsigned short h) {
    return __uint_as_float(((uint)h) << 16);
}
struct Split { unsigned short h, m, l; };
__device__ __forceinline__ Split split3(float x) {
    Split s;
    s.h = bf16h(x); float r = x - bf16f(s.h);
    s.m = bf16h(r); float r2 = r - bf16f(s.m);
    s.l = bf16h(r2);
    return s;
}

// A-side (gt, coords pre-scaled by -2) level pattern per 3-slot group:
// [h,h,m,h,l,m] -> k0..17; k18-20 = G2 h/m/l; k21-23 = 1.0
__device__ __forceinline__ short8 make_afrag(int g4, Split X, Split Y, Split Z,
                                             Split G2) {
    short8 f = {0,0,0,0,0,0,0,0};
    if (g4 == 0) {
        f[0]=(short)X.h; f[1]=(short)Y.h; f[2]=(short)Z.h;
        f[3]=(short)X.h; f[4]=(short)Y.h; f[5]=(short)Z.h;
        f[6]=(short)X.m; f[7]=(short)Y.m;
    } else if (g4 == 1) {
        f[0]=(short)Z.m; f[1]=(short)X.h; f[2]=(short)Y.h; f[3]=(short)Z.h;
        f[4]=(short)X.l; f[5]=(short)Y.l; f[6]=(short)Z.l; f[7]=(short)X.m;
    } else if (g4 == 2) {
        f[0]=(short)Y.m; f[1]=(short)Z.m;
        f[2]=(short)G2.h; f[3]=(short)G2.m; f[4]=(short)G2.l;
        f[5]=ONEB; f[6]=ONEB; f[7]=ONEB;
    }
    return f;
}
// B-side (pred, raw coords) level pattern per group:
// [h,m,h,l,h,m] -> k0..17; k18-20 = 1.0; k21-23 = P2 h/m/l
// Products per group vs A: hh, hm, mh, hl, lh, mm (ml+lm+ll dropped ~2^-25).
__device__ __forceinline__ short8 make_bfrag(int g4, Split X, Split Y, Split Z,
                                             Split P2) {
    short8 f = {0,0,0,0,0,0,0,0};
    if (g4 == 0) {
        f[0]=(short)X.h; f[1]=(short)Y.h; f[2]=(short)Z.h;
        f[3]=(short)X.m; f[4]=(short)Y.m; f[5]=(short)Z.m;
        f[6]=(short)X.h; f[7]=(short)Y.h;
    } else if (g4 == 1) {
        f[0]=(short)Z.h; f[1]=(short)X.l; f[2]=(short)Y.l; f[3]=(short)Z.l;
        f[4]=(short)X.h; f[5]=(short)Y.h; f[6]=(short)Z.h; f[7]=(short)X.m;
    } else if (g4 == 2) {
        f[0]=(short)Y.m; f[1]=(short)Z.m;
        f[2]=ONEB; f[3]=ONEB; f[4]=ONEB;
        f[5]=(short)P2.h; f[6]=(short)P2.m; f[7]=(short)P2.l;
    }
    return f;
}

// ---- prep: pred -> B-fragments (one thread per (batch,tile,lane)) ----
__global__ __launch_bounds__(TPBP) void chamfer_prep(
    const float* __restrict__ pred, short8* __restrict__ Bfrag)
{
    const int gid  = blockIdx.x * TPBP + threadIdx.x;   // 524288 total
    const int lane = gid & 63;
    const int ent  = gid >> 6;          // b*256 + tile
    const int b    = ent >> 8;
    const int tile = ent & 255;
    const int l15  = lane & 15, g4 = lane >> 4;
    const int pt   = tile * 16 + l15;

    const float* p = pred + ((size_t)(b * NPTS + pt)) * 3;
    float x = p[0], y = p[1], z = p[2];
    Split X = split3(x), Y = split3(y), Z = split3(z);
    Split P2 = split3(fmaf(x, x, fmaf(y, y, z * z)));
    Bfrag[gid] = make_bfrag(g4, X, Y, Z, P2);
}

// ---- main: per block = (batch, 128 gt rows); sweep all 4096 pred cols ----
__global__ __launch_bounds__(TPBM, 4) void chamfer_mfma(
    const float* __restrict__ gt,
    uint* __restrict__ wspred,
    const short8* __restrict__ Bfrag,
    float* __restrict__ out)
{
    const int bx    = blockIdx.x;      // 1024 = b(32) x panel(32)
    const int b     = bx >> 5;
    const int panel = bx & 31;
    const int tid   = threadIdx.x;
    const int lane  = tid & 63, wid = tid >> 6;
    const int rw    = wid >> 2;        // row half (64 gt rows)
    const int cq    = wid & 3;         // pred col quarter (1024 cols)
    const int g4    = lane >> 4, l15 = lane & 15;
    const int rowbase = panel * 128 + rw * 64;

    __shared__ float sred[128 * 4];    // [row_local][cq] gt-side partials
    __shared__ float sw[8];
    __shared__ uint  s_last;

    // Build A-frags: this wave's 64 gt rows, coords scaled by -2, g2 baked in.
    const float* gtb = gt + (size_t)b * NPTS * 3;
    short8 afr[4];
    float gm[4][4];
#pragma unroll
    for (int mt = 0; mt < 4; ++mt) {
        const int arow = rowbase + mt * 16 + l15;
        const float* ap = gtb + (size_t)arow * 3;
        float x = ap[0], y = ap[1], z = ap[2];
        Split X = split3(-2.0f * x), Y = split3(-2.0f * y), Z = split3(-2.0f * z);
        Split G2 = split3(fmaf(x, x, fmaf(y, y, z * z)));
        afr[mt] = make_afrag(g4, X, Y, Z, G2);
#pragma unroll
        for (int r = 0; r < 4; ++r) gm[mt][r] = 1e30f;
    }

    // Sweep this wave's 64 pred tiles (1024 cols). acc == d2 directly.
    const short8* bbase = Bfrag + ((size_t)(b * 256 + cq * 64)) * 64 + lane;
    uint*         wsp   = wspred + b * NPTS + cq * 1024 + l15;
    const f32x4 zero = {0.f, 0.f, 0.f, 0.f};

    for (int s = 0; s < 64; ++s) {
        short8 bfr = bbase[(size_t)s * 64];
        f32x4 acc[4];
#pragma unroll
        for (int mt = 0; mt < 4; ++mt)
            acc[mt] = __builtin_amdgcn_mfma_f32_16x16x32_bf16(
                afr[mt], bfr, zero, 0, 0, 0);

        float tmin = 1e30f;
#pragma unroll
        for (int mt = 0; mt < 4; ++mt) {
            gm[mt][0] = fminf(gm[mt][0], acc[mt][0]);   // 4x v_min
            gm[mt][1] = fminf(gm[mt][1], acc[mt][1]);
            gm[mt][2] = fminf(gm[mt][2], acc[mt][2]);
            gm[mt][3] = fminf(gm[mt][3], acc[mt][3]);
            tmin = fminf(fminf(acc[mt][0], acc[mt][1]), tmin);  // v_min3
            tmin = fminf(fminf(acc[mt][2], acc[mt][3]), tmin);  // v_min3
        }
        // pred-side: fold over the wave's 64 gt rows (cross row-groups)
        tmin = fminf(tmin, __shfl_xor(tmin, 16, 64));
        tmin = fminf(tmin, __shfl_xor(tmin, 32, 64));
        if (g4 == 0) {
            float dp = fmaxf(tmin, 1e-12f);   // >0 -> uint order == float order
            uint  mine = __float_as_uint(dp);
            uint* a = wsp + s * 16;
            if (mine < *a) atomicMin(a, mine);
        }
    }

    // gt-side: reduce gm across the 16 cols (l15 lanes) of each row-group.
#pragma unroll
    for (int mt = 0; mt < 4; ++mt)
#pragma unroll
        for (int r = 0; r < 4; ++r) {
            float v = gm[mt][r];
            v = fminf(v, __shfl_xor(v, 1, 64));
            v = fminf(v, __shfl_xor(v, 2, 64));
            v = fminf(v, __shfl_xor(v, 4, 64));
            v = fminf(v, __shfl_xor(v, 8, 64));
            gm[mt][r] = v;
        }
    if (l15 == 0) {
#pragma unroll
        for (int mt = 0; mt < 4; ++mt)
#pragma unroll
            for (int r = 0; r < 4; ++r)
                sred[(rw * 64 + mt * 16 + g4 * 4 + r) * 4 + cq] = gm[mt][r];
    }
    __syncthreads();

    float ssum = 0.0f;
    if (tid < 128) {
        float v = fminf(fminf(sred[tid*4], sred[tid*4+1]),
                        fminf(sred[tid*4+2], sred[tid*4+3]));
        ssum = sqrtf(fmaxf(v, 1e-12f));
    }
#pragma unroll
    for (int off = 32; off > 0; off >>= 1) ssum += __shfl_down(ssum, off, 64);
    if (lane == 0) sw[wid] = ssum;
    __syncthreads();
    if (tid == 0) {
        float t = sw[0]+sw[1]+sw[2]+sw[3]+sw[4]+sw[5]+sw[6]+sw[7];
        atomicAdd(out, t * (1.0f / 131072.0f));
    }

    // ---- per-batch finisher: last of 32 blocks sums the pred side ----
    __threadfence();
    if (tid == 0)
        s_last = (atomicAdd(&g_done[b], 1u) == 31u) ? 1u : 0u;
    __syncthreads();
    if (s_last) {
        __threadfence();   // acquire: all sibling blocks' atomicMins visible
        float s = 0.0f;
        for (int i = tid; i < NPTS; i += TPBM)
            s += sqrtf(__uint_as_float(wspred[b * NPTS + i]));
#pragma unroll
        for (int off = 32; off > 0; off >>= 1) s += __shfl_down(s, off, 64);
        if (lane == 0) sw[wid] = s;
        __syncthreads();
        if (tid == 0) {
            float t = sw[0]+sw[1]+sw[2]+sw[3]+sw[4]+sw[5]+sw[6]+sw[7];
            atomicAdd(out, t * (1.0f / 131072.0f));
            atomicExch(&g_done[b], 0u);   // replay-safe reset
        }
    }
}

extern "C" void kernel_launch(void* const* d_in, const int* in_sizes, int n_in,
                              void* d_out, int out_size, void* d_ws, size_t ws_size,
                              hipStream_t stream)
{
    const float* pred = (const float*)d_in[0];
    const float* gt   = (const float*)d_in[1];
    float* out        = (float*)d_out;

    // ws layout: [0,512K) wspred uints; [1M,9M) Bfrag (512K..1M unused)
    uint*   wspred = (uint*)d_ws;
    short8* Bfrag  = (short8*)((char*)d_ws + (1 << 20));

    hipMemsetAsync(d_ws, 0xFF, (size_t)(512 << 10), stream);  // atomicMin identity
    hipMemsetAsync(d_out, 0, sizeof(float), stream);

    chamfer_prep<<<dim3(GRID_PREP), dim3(TPBP), 0, stream>>>(pred, Bfrag);
    chamfer_mfma<<<dim3(GRID_MAIN), dim3(TPBM), 0, stream>>>(
        gt, wspred, Bfrag, out);
}

// Round 5
// 319.013 us; speedup vs baseline: 1.4684x; 1.4684x over previous
//
#include <hip/hip_runtime.h>
#include <math.h>

// ChamferLoss: pred [32,4096,3] f32, gt [32,4096,3] f32 -> scalar f32.
//
// R9 = R8 (correct MFMA d2-in-matrix, absmax 0.0) minus the in-loop global
// serialization. R8 counters: MfmaUtil 3.2 / VALUBusy 15.7 / HBM 2% -> all
// pipes idle = latency-bound on the per-iter guard load + atomicMin (the
// guarded line is hammered by 31 sibling blocks -> L2 round-trip per iter).
//
//  - In-loop pred-min merge is now a PLAIN LDS store: per s-iter the 16
//    folded col-mins land on distinct cols (s*16+l15 covers 1024 distinct
//    slots per wave) -> sPmin[rw][cq][1024], written exactly once, no init.
//  - Cross-block pred merge batched in the epilogue: fold rw pairs, then
//    8 coalesced guarded atomicMins per thread (was 64 dependent ones
//    inside the hot loop).
//  - Inner loop: 1 independent 16B global load + 4 MFMA + ~24 VALU min
//    + 2 shfl + 1 LDS store. No global round-trips.
//  - Everything else from R8 kept: prep builds B-frags with d2 baked into
//    K-slots (dot(-2g,p) + g2*1 + 1*p2), gt-side register fold, done-counter
//    per-batch finisher.
//
// Layouts (m89-verified family, 16x16x32 bf16):
//   A: row = lane&15, k = 8*(lane>>4)+i
//   B: col = lane&15, k = 8*(lane>>4)+i
//   C: col = lane&15, row = 4*(lane>>4)+reg

typedef short short8 __attribute__((ext_vector_type(8)));
typedef float f32x4 __attribute__((ext_vector_type(4)));
typedef unsigned int uint;

#define NPTS  4096
#define TPBM  512           // main: 8 waves = rowhalf(2) x colquarter(4)
#define TPBP  256
#define PANELS 32           // gt row-panels of 128 per batch
#define GRID_MAIN (32 * PANELS)
#define GRID_PREP ((32 * 256 * 64) / TPBP)   // one thread per frag-lane
#define ONEB ((short)0x3F80)                 // bf16 1.0

__device__ unsigned int g_done[32];   // zero-init; self-resetting per replay

// ---- bf16 split helpers (RNE) ----
__device__ __forceinline__ unsigned short bf16h(float f) {
    uint u = __float_as_uint(f);
    uint r = u + 0x7FFFu + ((u >> 16) & 1u);
    return (unsigned short)(r >> 16);
}
__device__ __forceinline__ float bf16f(unsigned short h) {
    return __uint_as_float(((uint)h) << 16);
}
struct Split { unsigned short h, m, l; };
__device__ __forceinline__ Split split3(float x) {
    Split s;
    s.h = bf16h(x); float r = x - bf16f(s.h);
    s.m = bf16h(r); float r2 = r - bf16f(s.m);
    s.l = bf16h(r2);
    return s;
}

// A-side (gt, coords pre-scaled by -2) level pattern per 3-slot group:
// [h,h,m,h,l,m] -> k0..17; k18-20 = G2 h/m/l; k21-23 = 1.0
__device__ __forceinline__ short8 make_afrag(int g4, Split X, Split Y, Split Z,
                                             Split G2) {
    short8 f = {0,0,0,0,0,0,0,0};
    if (g4 == 0) {
        f[0]=(short)X.h; f[1]=(short)Y.h; f[2]=(short)Z.h;
        f[3]=(short)X.h; f[4]=(short)Y.h; f[5]=(short)Z.h;
        f[6]=(short)X.m; f[7]=(short)Y.m;
    } else if (g4 == 1) {
        f[0]=(short)Z.m; f[1]=(short)X.h; f[2]=(short)Y.h; f[3]=(short)Z.h;
        f[4]=(short)X.l; f[5]=(short)Y.l; f[6]=(short)Z.l; f[7]=(short)X.m;
    } else if (g4 == 2) {
        f[0]=(short)Y.m; f[1]=(short)Z.m;
        f[2]=(short)G2.h; f[3]=(short)G2.m; f[4]=(short)G2.l;
        f[5]=ONEB; f[6]=ONEB; f[7]=ONEB;
    }
    return f;
}
// B-side (pred, raw coords) level pattern per group:
// [h,m,h,l,h,m] -> k0..17; k18-20 = 1.0; k21-23 = P2 h/m/l
// Products per group vs A: hh, hm, mh, hl, lh, mm (ml+lm+ll dropped ~2^-25).
__device__ __forceinline__ short8 make_bfrag(int g4, Split X, Split Y, Split Z,
                                             Split P2) {
    short8 f = {0,0,0,0,0,0,0,0};
    if (g4 == 0) {
        f[0]=(short)X.h; f[1]=(short)Y.h; f[2]=(short)Z.h;
        f[3]=(short)X.m; f[4]=(short)Y.m; f[5]=(short)Z.m;
        f[6]=(short)X.h; f[7]=(short)Y.h;
    } else if (g4 == 1) {
        f[0]=(short)Z.h; f[1]=(short)X.l; f[2]=(short)Y.l; f[3]=(short)Z.l;
        f[4]=(short)X.h; f[5]=(short)Y.h; f[6]=(short)Z.h; f[7]=(short)X.m;
    } else if (g4 == 2) {
        f[0]=(short)Y.m; f[1]=(short)Z.m;
        f[2]=ONEB; f[3]=ONEB; f[4]=ONEB;
        f[5]=(short)P2.h; f[6]=(short)P2.m; f[7]=(short)P2.l;
    }
    return f;
}

// ---- prep: pred -> B-fragments (one thread per (batch,tile,lane)) ----
__global__ __launch_bounds__(TPBP) void chamfer_prep(
    const float* __restrict__ pred, short8* __restrict__ Bfrag)
{
    const int gid  = blockIdx.x * TPBP + threadIdx.x;   // 524288 total
    const int lane = gid & 63;
    const int ent  = gid >> 6;          // b*256 + tile
    const int b    = ent >> 8;
    const int tile = ent & 255;
    const int l15  = lane & 15, g4 = lane >> 4;
    const int pt   = tile * 16 + l15;

    const float* p = pred + ((size_t)(b * NPTS + pt)) * 3;
    float x = p[0], y = p[1], z = p[2];
    Split X = split3(x), Y = split3(y), Z = split3(z);
    Split P2 = split3(fmaf(x, x, fmaf(y, y, z * z)));
    Bfrag[gid] = make_bfrag(g4, X, Y, Z, P2);
}

// ---- main: per block = (batch, 128 gt rows); sweep all 4096 pred cols ----
__global__ __launch_bounds__(TPBM, 4) void chamfer_mfma(
    const float* __restrict__ gt,
    uint* __restrict__ wspred,
    const short8* __restrict__ Bfrag,
    float* __restrict__ out)
{
    const int bx    = blockIdx.x;      // 1024 = b(32) x panel(32)
    const int b     = bx >> 5;
    const int panel = bx & 31;
    const int tid   = threadIdx.x;
    const int lane  = tid & 63, wid = tid >> 6;
    const int rw    = wid >> 2;        // row half (64 gt rows)
    const int cq    = wid & 3;         // pred col quarter (1024 cols)
    const int g4    = lane >> 4, l15 = lane & 15;
    const int rowbase = panel * 128 + rw * 64;

    __shared__ float sPmin[2][4][1024];  // [rw][cq][col] pred-side, 32 KB
    __shared__ float sred[128 * 4];      // [row_local][cq] gt-side partials
    __shared__ float sw[8];
    __shared__ uint  s_last;

    // Build A-frags: this wave's 64 gt rows, coords scaled by -2, g2 baked in.
    const float* gtb = gt + (size_t)b * NPTS * 3;
    short8 afr[4];
    float gm[4][4];
#pragma unroll
    for (int mt = 0; mt < 4; ++mt) {
        const int arow = rowbase + mt * 16 + l15;
        const float* ap = gtb + (size_t)arow * 3;
        float x = ap[0], y = ap[1], z = ap[2];
        Split X = split3(-2.0f * x), Y = split3(-2.0f * y), Z = split3(-2.0f * z);
        Split G2 = split3(fmaf(x, x, fmaf(y, y, z * z)));
        afr[mt] = make_afrag(g4, X, Y, Z, G2);
#pragma unroll
        for (int r = 0; r < 4; ++r) gm[mt][r] = 1e30f;
    }

    // Sweep this wave's 64 pred tiles (1024 cols). acc == d2 directly.
    // No global ops in the loop besides the independent 16B Bfrag load.
    const short8* bbase = Bfrag + ((size_t)(b * 256 + cq * 64)) * 64 + lane;
    const f32x4 zero = {0.f, 0.f, 0.f, 0.f};

#pragma unroll 2
    for (int s = 0; s < 64; ++s) {
        short8 bfr = bbase[(size_t)s * 64];
        f32x4 acc[4];
#pragma unroll
        for (int mt = 0; mt < 4; ++mt)
            acc[mt] = __builtin_amdgcn_mfma_f32_16x16x32_bf16(
                afr[mt], bfr, zero, 0, 0, 0);

        float tmin = 1e30f;
#pragma unroll
        for (int mt = 0; mt < 4; ++mt) {
            gm[mt][0] = fminf(gm[mt][0], acc[mt][0]);   // 4x v_min
            gm[mt][1] = fminf(gm[mt][1], acc[mt][1]);
            gm[mt][2] = fminf(gm[mt][2], acc[mt][2]);
            gm[mt][3] = fminf(gm[mt][3], acc[mt][3]);
            tmin = fminf(fminf(acc[mt][0], acc[mt][1]), tmin);  // v_min3
            tmin = fminf(fminf(acc[mt][2], acc[mt][3]), tmin);  // v_min3
        }
        // fold over the wave's 64 gt rows (cross row-groups)
        tmin = fminf(tmin, __shfl_xor(tmin, 16, 64));
        tmin = fminf(tmin, __shfl_xor(tmin, 32, 64));
        // distinct col per (s,l15): plain store, written exactly once
        if (g4 == 0) sPmin[rw][cq][s * 16 + l15] = tmin;
    }

    // gt-side: reduce gm across the 16 cols (l15 lanes) of each row-group.
#pragma unroll
    for (int mt = 0; mt < 4; ++mt)
#pragma unroll
        for (int r = 0; r < 4; ++r) {
            float v = gm[mt][r];
            v = fminf(v, __shfl_xor(v, 1, 64));
            v = fminf(v, __shfl_xor(v, 2, 64));
            v = fminf(v, __shfl_xor(v, 4, 64));
            v = fminf(v, __shfl_xor(v, 8, 64));
            gm[mt][r] = v;
        }

    __syncthreads();   // sPmin complete & visible

    // pred-side epilogue: batched guarded atomicMin, 8 coalesced cols/thread
    uint* wsb = wspred + (size_t)b * NPTS;
    for (int c = tid; c < NPTS; c += TPBM) {
        const int q = c >> 10, idx = c & 1023;
        float v  = fminf(sPmin[0][q][idx], sPmin[1][q][idx]);
        float dp = fmaxf(v, 1e-12f);   // >0 -> uint order == float order
        uint mine = __float_as_uint(dp);
        if (mine < wsb[c]) atomicMin(&wsb[c], mine);
    }

    if (l15 == 0) {
#pragma unroll
        for (int mt = 0; mt < 4; ++mt)
#pragma unroll
            for (int r = 0; r < 4; ++r)
                sred[(rw * 64 + mt * 16 + g4 * 4 + r) * 4 + cq] = gm[mt][r];
    }
    __syncthreads();

    float ssum = 0.0f;
    if (tid < 128) {
        float v = fminf(fminf(sred[tid*4], sred[tid*4+1]),
                        fminf(sred[tid*4+2], sred[tid*4+3]));
        ssum = sqrtf(fmaxf(v, 1e-12f));
    }
#pragma unroll
    for (int off = 32; off > 0; off >>= 1) ssum += __shfl_down(ssum, off, 64);
    if (lane == 0) sw[wid] = ssum;
    __syncthreads();
    if (tid == 0) {
        float t = sw[0]+sw[1]+sw[2]+sw[3]+sw[4]+sw[5]+sw[6]+sw[7];
        atomicAdd(out, t * (1.0f / 131072.0f));
    }

    // ---- per-batch finisher: last of 32 blocks sums the pred side ----
    __threadfence();
    if (tid == 0)
        s_last = (atomicAdd(&g_done[b], 1u) == 31u) ? 1u : 0u;
    __syncthreads();
    if (s_last) {
        __threadfence();   // acquire: all sibling blocks' atomicMins visible
        float s = 0.0f;
        for (int i = tid; i < NPTS; i += TPBM)
            s += sqrtf(__uint_as_float(wspred[(size_t)b * NPTS + i]));
#pragma unroll
        for (int off = 32; off > 0; off >>= 1) s += __shfl_down(s, off, 64);
        if (lane == 0) sw[wid] = s;
        __syncthreads();
        if (tid == 0) {
            float t = sw[0]+sw[1]+sw[2]+sw[3]+sw[4]+sw[5]+sw[6]+sw[7];
            atomicAdd(out, t * (1.0f / 131072.0f));
            atomicExch(&g_done[b], 0u);   // replay-safe reset
        }
    }
}

extern "C" void kernel_launch(void* const* d_in, const int* in_sizes, int n_in,
                              void* d_out, int out_size, void* d_ws, size_t ws_size,
                              hipStream_t stream)
{
    const float* pred = (const float*)d_in[0];
    const float* gt   = (const float*)d_in[1];
    float* out        = (float*)d_out;

    // ws layout: [0,512K) wspred uints; [1M,9M) Bfrag (512K..1M unused)
    uint*   wspred = (uint*)d_ws;
    short8* Bfrag  = (short8*)((char*)d_ws + (1 << 20));

    hipMemsetAsync(d_ws, 0xFF, (size_t)(512 << 10), stream);  // atomicMin identity
    hipMemsetAsync(d_out, 0, sizeof(float), stream);

    chamfer_prep<<<dim3(GRID_PREP), dim3(TPBP), 0, stream>>>(pred, Bfrag);
    chamfer_mfma<<<dim3(GRID_MAIN), dim3(TPBM), 0, stream>>>(
        gt, wspred, Bfrag, out);
}

// Round 6
// 128.344 us; speedup vs baseline: 3.6498x; 2.4856x over previous
//
#include <hip/hip_runtime.h>
#include <math.h>

// ChamferLoss: pred [32,4096,3] f32, gt [32,4096,3] f32 -> scalar f32.
//
// R10. R9 counters: MfmaUtil 4.9 / VALUBusy 11.2 / HBM 2.3% -> ALL pipes
// idle; MFMA-busy time == the 13.5us theoretical floor, wall 275us. The
// inner loop was latency-serialized: per-iter global Bfrag load (L2/HBM
// round-trip) + 2 serial ds_bpermute folds; plus __threadfence / device
// atomics forcing per-XCD L2 invalidations (FETCH 38-52MB vs 8MB Bfrag =
// 5-6x refetch). R10 removes every latency source from the loop:
//  - Bfrag LDS-staged in 32KB chunks (8 tiles/cq, single-buffer, 2 barriers
//    per chunk) -> inner loop is ds_read_b128 + 4 MFMA + ~26 VALU only.
//  - No shuffles in loop: per-lane 16-row tmin merges via LDS atomicMin on
//    uint-ordered sPmin[4096] (g4 x rw folds happen in the LDS atomic unit).
//  - No __threadfence / done-counter / atomicAdd in main: gt-side partial
//    sum -> plain store wsgt[bx]; pred-side -> epilogue guarded atomicMin;
//    tiny chamfer_finish (128 blocks) does the final sums.
//  - LDS 32+16+2KB ~ 50KB -> 3 blocks/CU.
// Numerics identical to R8/R9 (absmax 0.0 twice): d2 fully inside MFMA
// (dot(-2g,p) slots 0-17, g2*1 slots 18-20, 1*p2 slots 21-23).
//
// Layouts (m89-verified family, 16x16x32 bf16):
//   A: row = lane&15, k = 8*(lane>>4)+i
//   B: col = lane&15, k = 8*(lane>>4)+i
//   C: col = lane&15, row = 4*(lane>>4)+reg

typedef short short8 __attribute__((ext_vector_type(8)));
typedef float f32x4 __attribute__((ext_vector_type(4)));
typedef unsigned int uint;

#define NPTS  4096
#define TPBM  512           // main: 8 waves = rowhalf(2) x colquarter(4)
#define TPBP  256
#define PANELS 32           // gt row-panels of 128 per batch
#define GRID_MAIN (32 * PANELS)
#define GRID_PREP ((32 * 256 * 64) / TPBP)   // one thread per frag-lane
#define ONEB ((short)0x3F80)                 // bf16 1.0
#define CHT  8              // B-tiles per cq per chunk
#define NCH  8              // chunks: 64 tiles/cq / CHT

// ---- bf16 split helpers (RNE) ----
__device__ __forceinline__ unsigned short bf16h(float f) {
    uint u = __float_as_uint(f);
    uint r = u + 0x7FFFu + ((u >> 16) & 1u);
    return (unsigned short)(r >> 16);
}
__device__ __forceinline__ float bf16f(unsigned short h) {
    return __uint_as_float(((uint)h) << 16);
}
struct Split { unsigned short h, m, l; };
__device__ __forceinline__ Split split3(float x) {
    Split s;
    s.h = bf16h(x); float r = x - bf16f(s.h);
    s.m = bf16h(r); float r2 = r - bf16f(s.m);
    s.l = bf16h(r2);
    return s;
}

// A-side (gt, coords pre-scaled by -2) level pattern per 3-slot group:
// [h,h,m,h,l,m] -> k0..17; k18-20 = G2 h/m/l; k21-23 = 1.0
__device__ __forceinline__ short8 make_afrag(int g4, Split X, Split Y, Split Z,
                                             Split G2) {
    short8 f = {0,0,0,0,0,0,0,0};
    if (g4 == 0) {
        f[0]=(short)X.h; f[1]=(short)Y.h; f[2]=(short)Z.h;
        f[3]=(short)X.h; f[4]=(short)Y.h; f[5]=(short)Z.h;
        f[6]=(short)X.m; f[7]=(short)Y.m;
    } else if (g4 == 1) {
        f[0]=(short)Z.m; f[1]=(short)X.h; f[2]=(short)Y.h; f[3]=(short)Z.h;
        f[4]=(short)X.l; f[5]=(short)Y.l; f[6]=(short)Z.l; f[7]=(short)X.m;
    } else if (g4 == 2) {
        f[0]=(short)Y.m; f[1]=(short)Z.m;
        f[2]=(short)G2.h; f[3]=(short)G2.m; f[4]=(short)G2.l;
        f[5]=ONEB; f[6]=ONEB; f[7]=ONEB;
    }
    return f;
}
// B-side (pred, raw coords) level pattern per group:
// [h,m,h,l,h,m] -> k0..17; k18-20 = 1.0; k21-23 = P2 h/m/l
// Products per group vs A: hh, hm, mh, hl, lh, mm (ml+lm+ll dropped ~2^-25).
__device__ __forceinline__ short8 make_bfrag(int g4, Split X, Split Y, Split Z,
                                             Split P2) {
    short8 f = {0,0,0,0,0,0,0,0};
    if (g4 == 0) {
        f[0]=(short)X.h; f[1]=(short)Y.h; f[2]=(short)Z.h;
        f[3]=(short)X.m; f[4]=(short)Y.m; f[5]=(short)Z.m;
        f[6]=(short)X.h; f[7]=(short)Y.h;
    } else if (g4 == 1) {
        f[0]=(short)Z.h; f[1]=(short)X.l; f[2]=(short)Y.l; f[3]=(short)Z.l;
        f[4]=(short)X.h; f[5]=(short)Y.h; f[6]=(short)Z.h; f[7]=(short)X.m;
    } else if (g4 == 2) {
        f[0]=(short)Y.m; f[1]=(short)Z.m;
        f[2]=ONEB; f[3]=ONEB; f[4]=ONEB;
        f[5]=(short)P2.h; f[6]=(short)P2.m; f[7]=(short)P2.l;
    }
    return f;
}

// ---- prep: pred -> B-fragments (one thread per (batch,tile,lane)) ----
__global__ __launch_bounds__(TPBP) void chamfer_prep(
    const float* __restrict__ pred, short8* __restrict__ Bfrag)
{
    const int gid  = blockIdx.x * TPBP + threadIdx.x;   // 524288 total
    const int lane = gid & 63;
    const int ent  = gid >> 6;          // b*256 + tile
    const int b    = ent >> 8;
    const int tile = ent & 255;
    const int l15  = lane & 15, g4 = lane >> 4;
    const int pt   = tile * 16 + l15;

    const float* p = pred + ((size_t)(b * NPTS + pt)) * 3;
    float x = p[0], y = p[1], z = p[2];
    Split X = split3(x), Y = split3(y), Z = split3(z);
    Split P2 = split3(fmaf(x, x, fmaf(y, y, z * z)));
    Bfrag[gid] = make_bfrag(g4, X, Y, Z, P2);
}

// ---- main: per block = (batch, 128 gt rows); sweep all 4096 pred cols ----
__global__ __launch_bounds__(TPBM, 4) void chamfer_mfma(
    const float* __restrict__ gt,
    uint* __restrict__ wspred,
    float* __restrict__ wsgt,
    const short8* __restrict__ Bfrag)
{
    const int bx    = blockIdx.x;      // 1024 = b(32) x panel(32)
    const int b     = bx >> 5;
    const int panel = bx & 31;
    const int tid   = threadIdx.x;
    const int lane  = tid & 63, wid = tid >> 6;
    const int rw    = wid >> 2;        // row half (64 gt rows)
    const int cq    = wid & 3;         // pred col quarter (1024 cols)
    const int g4    = lane >> 4, l15 = lane & 15;
    const int rowbase = panel * 128 + rw * 64;

    __shared__ short8 sB[4 * CHT * 64];   // 32 KB: [cq][tile][lane]
    __shared__ uint   sPmin[NPTS];        // 16 KB: col-mins, uint-ordered
    __shared__ float  sred[128 * 4];      // gt-side [row_local][cq]
    __shared__ float  sw[8];

    // init sPmin (visible after the first chunk barrier)
    for (int c = tid; c < NPTS; c += TPBM) sPmin[c] = 0x7F7FFFFFu;

    // Build A-frags: this wave's 64 gt rows, coords scaled by -2, g2 baked in.
    const float* gtb = gt + (size_t)b * NPTS * 3;
    short8 afr[4];
    float gm[4][4];
#pragma unroll
    for (int mt = 0; mt < 4; ++mt) {
        const int arow = rowbase + mt * 16 + l15;
        const float* ap = gtb + (size_t)arow * 3;
        float x = ap[0], y = ap[1], z = ap[2];
        Split X = split3(-2.0f * x), Y = split3(-2.0f * y), Z = split3(-2.0f * z);
        Split G2 = split3(fmaf(x, x, fmaf(y, y, z * z)));
        afr[mt] = make_afrag(g4, X, Y, Z, G2);
#pragma unroll
        for (int r = 0; r < 4; ++r) gm[mt][r] = 1e30f;
    }

    const size_t bfbase = (size_t)b * 256 * 64;   // short8 entries
    const f32x4 zero = {0.f, 0.f, 0.f, 0.f};

    for (int ch = 0; ch < NCH; ++ch) {
        __syncthreads();   // prior chunk's reads done (ch=0: init visible)
        // stage 2048 entries (32 KB), 4 per thread, 1KB-contiguous runs
#pragma unroll
        for (int ps = 0; ps < 4; ++ps) {
            const int u   = ps * TPBM + tid;
            const int ucq = u >> 9, ut = (u >> 6) & 7, ul = u & 63;
            sB[u] = Bfrag[bfbase + ((size_t)(ucq * 64 + ch * CHT + ut) << 6) + ul];
        }
        __syncthreads();   // stage visible

#pragma unroll
        for (int t = 0; t < CHT; ++t) {
            short8 bfr = sB[(cq * CHT + t) * 64 + lane];
            f32x4 acc[4];
#pragma unroll
            for (int mt = 0; mt < 4; ++mt)
                acc[mt] = __builtin_amdgcn_mfma_f32_16x16x32_bf16(
                    afr[mt], bfr, zero, 0, 0, 0);

            // gt-side: running row-mins in registers
            float tmin = 1e30f;
#pragma unroll
            for (int mt = 0; mt < 4; ++mt) {
                gm[mt][0] = fminf(gm[mt][0], acc[mt][0]);
                gm[mt][1] = fminf(gm[mt][1], acc[mt][1]);
                gm[mt][2] = fminf(gm[mt][2], acc[mt][2]);
                gm[mt][3] = fminf(gm[mt][3], acc[mt][3]);
                tmin = fminf(fminf(acc[mt][0], acc[mt][1]), tmin);  // v_min3
                tmin = fminf(fminf(acc[mt][2], acc[mt][3]), tmin);  // v_min3
            }
            // pred-side: per-lane 16-row min -> LDS atomic (folds g4 & rw)
            const float dp = fmaxf(tmin, 1e-12f);  // >0: uint order == float
            atomicMin(&sPmin[cq * 1024 + (ch * CHT + t) * 16 + l15],
                      __float_as_uint(dp));
        }
    }
    __syncthreads();   // sPmin complete

    // pred-side epilogue: batched guarded atomicMin, 8 coalesced cols/thread
    uint* wsb = wspred + (size_t)b * NPTS;
    for (int c = tid; c < NPTS; c += TPBM) {
        const uint mine = sPmin[c];
        if (mine < wsb[c]) atomicMin(&wsb[c], mine);
    }

    // gt-side: reduce gm across the 16 cols (l15 lanes) of each row-group.
#pragma unroll
    for (int mt = 0; mt < 4; ++mt)
#pragma unroll
        for (int r = 0; r < 4; ++r) {
            float v = gm[mt][r];
            v = fminf(v, __shfl_xor(v, 1, 64));
            v = fminf(v, __shfl_xor(v, 2, 64));
            v = fminf(v, __shfl_xor(v, 4, 64));
            v = fminf(v, __shfl_xor(v, 8, 64));
            gm[mt][r] = v;
        }
    if (l15 == 0) {
#pragma unroll
        for (int mt = 0; mt < 4; ++mt)
#pragma unroll
            for (int r = 0; r < 4; ++r)
                sred[(rw * 64 + mt * 16 + g4 * 4 + r) * 4 + cq] = gm[mt][r];
    }
    __syncthreads();

    float ssum = 0.0f;
    if (tid < 128) {
        float v = fminf(fminf(sred[tid*4], sred[tid*4+1]),
                        fminf(sred[tid*4+2], sred[tid*4+3]));
        ssum = sqrtf(fmaxf(v, 1e-12f));
    }
#pragma unroll
    for (int off = 32; off > 0; off >>= 1) ssum += __shfl_down(ssum, off, 64);
    if (lane == 0) sw[wid] = ssum;
    __syncthreads();
    if (tid == 0)
        wsgt[bx] = sw[0]+sw[1]+sw[2]+sw[3]+sw[4]+sw[5]+sw[6]+sw[7];  // plain
}

// ---- finish: sum sqrt(pred mins) + gt partials -> out ----
__global__ __launch_bounds__(TPBP) void chamfer_finish(
    const uint* __restrict__ wspred, const float* __restrict__ wsgt,
    float* __restrict__ out)
{
    __shared__ float swv[TPBP / 64];
    const int tid  = threadIdx.x;
    const int base = blockIdx.x * (TPBP * 4) + tid;   // 128 blocks x 1024

    float s = 0.0f;
#pragma unroll
    for (int r = 0; r < 4; ++r)
        s += sqrtf(__uint_as_float(wspred[base + r * TPBP]));
    if (blockIdx.x == 0) {
#pragma unroll
        for (int r = 0; r < 4; ++r)
            s += wsgt[tid + r * TPBP];   // 1024 per-block gt partial sums
    }

#pragma unroll
    for (int off = 32; off > 0; off >>= 1) s += __shfl_down(s, off, 64);
    const int wid = tid >> 6, lane = tid & 63;
    if (lane == 0) swv[wid] = s;
    __syncthreads();
    if (tid == 0) {
        float tot = swv[0] + swv[1] + swv[2] + swv[3];
        atomicAdd(out, tot * (1.0f / 131072.0f));
    }
}

extern "C" void kernel_launch(void* const* d_in, const int* in_sizes, int n_in,
                              void* d_out, int out_size, void* d_ws, size_t ws_size,
                              hipStream_t stream)
{
    const float* pred = (const float*)d_in[0];
    const float* gt   = (const float*)d_in[1];
    float* out        = (float*)d_out;

    // ws layout: [0,512K) wspred uints; [512K,+4K) wsgt; [1M,9M) Bfrag
    uint*   wspred = (uint*)d_ws;
    float*  wsgt   = (float*)((char*)d_ws + (512 << 10));
    short8* Bfrag  = (short8*)((char*)d_ws + (1 << 20));

    hipMemsetAsync(d_ws, 0xFF, (size_t)(512 << 10), stream);  // atomicMin identity
    hipMemsetAsync(d_out, 0, sizeof(float), stream);

    chamfer_prep<<<dim3(GRID_PREP), dim3(TPBP), 0, stream>>>(pred, Bfrag);
    chamfer_mfma<<<dim3(GRID_MAIN), dim3(TPBM), 0, stream>>>(
        gt, wspred, wsgt, Bfrag);
    chamfer_finish<<<dim3(128), dim3(TPBP), 0, stream>>>(wspred, wsgt, out);
}